// Round 4
// baseline (1118.478 us; speedup 1.0000x reference)
//
#include <hip/hip_runtime.h>
#include <hip/hip_fp16.h>
#include <math.h>

#define NN 20000
#define EE 200000
// MUL=128, D=512, EDGE_ATTR=32, HID=32

__device__ __forceinline__ float sspf(float x){
    float sp = (x > 20.f) ? x : log1pf(expf(x));
    return sp - 0.69314718056f;
}

__device__ __forceinline__ void fma8(float* acc, const float* base, float w){
    const float4 a = ((const float4*)base)[0];
    const float4 b = ((const float4*)base)[1];
    acc[0]+=a.x*w; acc[1]+=a.y*w; acc[2]+=a.z*w; acc[3]+=a.w*w;
    acc[4]+=b.x*w; acc[5]+=b.y*w; acc[6]+=b.z*w; acc[7]+=b.w*w;
}

// ---------------- K1: pre irrep_linear -> p1, sdst (p0 consumed in-LDS) ----
__global__ __launch_bounds__(256) void k_pre(
    const float* __restrict__ x, const float* __restrict__ Wp0,
    const float* __restrict__ bp0, const float* __restrict__ Wp1,
    const float* __restrict__ Ws1,
    float* __restrict__ p1, float* __restrict__ sdst)
{
    __shared__ float xl[512][8];    // transposed [feature][node]
    __shared__ float p0l[8][128];
    const int tid = threadIdx.x;
    const int n0 = blockIdx.x * 8;

    for (int it = 0; it < 4; ++it){
        int idx = tid + 256*it;           // 0..1023 float4 slots
        int node = idx >> 7, o4 = idx & 127;
        float4 v = ((const float4*)(x + (size_t)(n0+node)*512))[o4];
        xl[o4*4+0][node]=v.x; xl[o4*4+1][node]=v.y;
        xl[o4*4+2][node]=v.z; xl[o4*4+3][node]=v.w;
    }
    __syncthreads();

    const int j = tid;
    float acc1[8] = {0,0,0,0,0,0,0,0};
    float acc2[8] = {0,0,0,0,0,0,0,0};
    const int o2 = j + 128;               // p1-index in [128,384)
    const int v2 = o2/3, m2 = o2%3;

    if (j < 128){
        for (int u = 0; u < 128; ++u){
            float w1 = Wp0[u*128 + j];
            float w2 = Wp1[u*128 + v2];
            fma8(acc1, &xl[u][0], w1);
            fma8(acc2, &xl[128 + u*3 + m2][0], w2);
        }
        float b = bp0[j];
        #pragma unroll
        for (int n = 0; n < 8; ++n) p0l[n][j] = acc1[n] + b;
    } else {
        const int o1 = j - 128, v1 = o1/3, m1 = o1%3;
        for (int u = 0; u < 128; ++u){
            float w1 = Wp1[u*128 + v1];
            float w2 = Wp1[u*128 + v2];
            fma8(acc1, &xl[128 + u*3 + m1][0], w1);
            fma8(acc2, &xl[128 + u*3 + m2][0], w2);
        }
        #pragma unroll
        for (int n = 0; n < 8; ++n) p1[(size_t)(n0+n)*384 + (j-128)] = acc1[n];
    }
    #pragma unroll
    for (int n = 0; n < 8; ++n) p1[(size_t)(n0+n)*384 + o2] = acc2[n];
    __syncthreads();

    // sdst = p0 @ (Ws1[0:128] + Ws1[128:256])  (the dst-only part of s0@W_s1)
    {
        int n = tid >> 5, h = tid & 31;
        float s = 0.f;
        for (int u = 0; u < 128; ++u){
            float wc = Ws1[u*32 + h] + Ws1[(128+u)*32 + h];
            s += p0l[n][u] * wc;
        }
        sdst[(size_t)(n0+n)*32 + h] = s;
    }
}

// ---------------- K2: gate + node irrep_linear -> self_x -------------------
__global__ __launch_bounds__(256) void k_gate_nd(
    const float* __restrict__ x,
    const float* __restrict__ Wg1, const float* __restrict__ bg1,
    const float* __restrict__ Wg2, const float* __restrict__ bg2,
    const float* __restrict__ Wnd0, const float* __restrict__ bnd0,
    const float* __restrict__ Wnd1,
    float* __restrict__ self_x)
{
    __shared__ float xl[512][8];
    __shared__ float tl[256][8];   // t, then reused for g
    __shared__ float hl[256][8];
    const int tid = threadIdx.x;
    const int n0 = blockIdx.x * 8;

    for (int it = 0; it < 4; ++it){
        int idx = tid + 256*it;
        int node = idx >> 7, o4 = idx & 127;
        float4 v = ((const float4*)(x + (size_t)(n0+node)*512))[o4];
        xl[o4*4+0][node]=v.x; xl[o4*4+1][node]=v.y;
        xl[o4*4+2][node]=v.z; xl[o4*4+3][node]=v.w;
    }
    __syncthreads();

    { // t = [x0, n1]
        int jj = tid;
        if (jj < 128){
            #pragma unroll
            for (int n = 0; n < 8; ++n) tl[jj][n] = xl[jj][n];
        } else {
            int u = jj - 128;
            #pragma unroll
            for (int n = 0; n < 8; ++n){
                float a = xl[128+u*3][n], b = xl[128+u*3+1][n], c = xl[128+u*3+2][n];
                tl[jj][n] = sqrtf((a*a + b*b + c*c) * (1.f/3.f));
            }
        }
    }
    __syncthreads();

    { // h = silu(t @ Wg1 + bg1)
        float acc[8] = {0,0,0,0,0,0,0,0};
        for (int k = 0; k < 256; ++k){
            float w = Wg1[k*256 + tid];
            fma8(acc, &tl[k][0], w);
        }
        float b = bg1[tid];
        #pragma unroll
        for (int n = 0; n < 8; ++n){
            float v = acc[n] + b;
            hl[tid][n] = v / (1.f + expf(-v));
        }
    }
    __syncthreads();

    { // g = h @ Wg2 + bg2  (stored into tl; tl is dead after the barrier)
        float acc[8] = {0,0,0,0,0,0,0,0};
        for (int k = 0; k < 256; ++k){
            float w = Wg2[k*256 + tid];
            fma8(acc, &hl[k][0], w);
        }
        float b = bg2[tid];
        #pragma unroll
        for (int n = 0; n < 8; ++n) tl[tid][n] = acc[n] + b;
    }
    __syncthreads();

    { // xg in-place into xl
        int jj = tid;
        if (jj < 128){
            #pragma unroll
            for (int n = 0; n < 8; ++n) xl[jj][n] = tl[jj][n];
        } else {
            int u = jj - 128;
            #pragma unroll
            for (int n = 0; n < 8; ++n){
                float g1 = tl[128+u][n];
                xl[128+u*3  ][n] *= g1;
                xl[128+u*3+1][n] *= g1;
                xl[128+u*3+2][n] *= g1;
            }
        }
    }
    __syncthreads();

    // nd irrep_linear
    const int j = tid;
    float acc1[8] = {0,0,0,0,0,0,0,0};
    float acc2[8] = {0,0,0,0,0,0,0,0};
    const int o2 = j + 128;
    const int v2 = o2/3, m2 = o2%3;
    if (j < 128){
        for (int u = 0; u < 128; ++u){
            float w1 = Wnd0[u*128 + j];
            float w2 = Wnd1[u*128 + v2];
            fma8(acc1, &xl[u][0], w1);
            fma8(acc2, &xl[128 + u*3 + m2][0], w2);
        }
        float b = bnd0[j];
        #pragma unroll
        for (int n = 0; n < 8; ++n) self_x[(size_t)(n0+n)*512 + j] = acc1[n] + b;
    } else {
        const int o1 = j - 128, v1 = o1/3, m1 = o1%3;
        for (int u = 0; u < 128; ++u){
            float w1 = Wnd1[u*128 + v1];
            float w2 = Wnd1[u*128 + v2];
            fma8(acc1, &xl[128 + u*3 + m1][0], w1);
            fma8(acc2, &xl[128 + u*3 + m2][0], w2);
        }
        #pragma unroll
        for (int n = 0; n < 8; ++n) self_x[(size_t)(n0+n)*512 + j] = acc1[n];
    }
    #pragma unroll
    for (int n = 0; n < 8; ++n) self_x[(size_t)(n0+n)*512 + j + 256] = acc2[n];
}

// ---------------- CSR build: count, scan, fill (arrays hosted in d_out) ----
__global__ __launch_bounds__(256) void k_count(
    const int* __restrict__ eidx, int* __restrict__ cnt)
{
    int e = blockIdx.x * 256 + threadIdx.x;
    if (e < EE){
        int d = eidx[e];
        if (d >= 0 && d < NN) atomicAdd(&cnt[d], 1);
    }
}

__global__ __launch_bounds__(256) void k_scan(
    const int* __restrict__ cnt, int* __restrict__ rowptr, int* __restrict__ cur)
{
    __shared__ int part[256];
    const int t = threadIdx.x;
    const int CHUNK = 79;             // 256*79 = 20224 >= 20000
    const int base = t * CHUNK;
    int s = 0;
    for (int i = 0; i < CHUNK; ++i){
        int idx = base + i;
        if (idx < NN) s += cnt[idx];
    }
    part[t] = s;
    __syncthreads();
    for (int off = 1; off < 256; off <<= 1){
        int v = (t >= off) ? part[t-off] : 0;
        __syncthreads();
        part[t] += v;
        __syncthreads();
    }
    int run = (t == 0) ? 0 : part[t-1];
    for (int i = 0; i < CHUNK; ++i){
        int idx = base + i;
        if (idx < NN){
            rowptr[idx] = run;
            cur[idx]    = run;
            run += cnt[idx];
        }
    }
    if (t == 255) rowptr[NN] = run;
}

__global__ __launch_bounds__(256) void k_fill(
    const int* __restrict__ eidx, int* __restrict__ cur, int2* __restrict__ ebuf,
    int* __restrict__ dstbuf)
{
    int e = blockIdx.x * 256 + threadIdx.x;
    if (e < EE){
        int dst = eidx[e];
        int src = eidx[EE + e];
        if (dst >= 0 && dst < NN){
            int pos = atomicAdd(&cur[dst], 1);
            if (pos >= 0 && pos < EE){
                ebuf[pos] = make_int2(e, src);
                dstbuf[pos] = dst;
            }
        }
    }
}

// ---------------- K3: edge features in CSR order -> fbuf, sbuf -------------
// Wave-per-edge ip1: no p1 row staging (rows read once -> straight to regs).
// dst rows are L1/L2-resident (CSR-consecutive edges share dst); src rows are
// the only true random gather. LDS down to ~6.3 KB -> occupancy uncapped.
__global__ __launch_bounds__(256) void k_edge_pre(
    const float* __restrict__ p1g, const float* __restrict__ sdst,
    const float* __restrict__ ea,
    const int2* __restrict__ ebuf, const int* __restrict__ dstbuf,
    const float* __restrict__ Wf1, const float* __restrict__ Ws1,
    float* __restrict__ fbuf, float* __restrict__ sbuf)
{
    __shared__ float ip1l[8][128];
    __shared__ float eal[8][32], sdl[8][32];
    __shared__ int eidl[8], srcl[8], dstl[8];
    const int tid = threadIdx.x;
    const long e0 = (long)blockIdx.x * 8;

    if (tid < 8){
        int2 pe = ebuf[e0 + tid];
        if (!(pe.x >= 0 && pe.x < EE)) pe.x = 0;
        if (!(pe.y >= 0 && pe.y < NN)) pe.y = 0;
        int d = dstbuf[e0 + tid];
        if (!(d >= 0 && d < NN)) d = 0;
        eidl[tid] = pe.x; srcl[tid] = pe.y; dstl[tid] = d;
    }
    __syncthreads();

    // phase 1: wave wv computes ip1 for edges 2wv, 2wv+1 (lane ch u, u+64)
    {
        const int wv = tid >> 6, lane = tid & 63;
        #pragma unroll
        for (int t = 0; t < 2; ++t){
            const int e = wv*2 + t;
            const float* pd = p1g + (size_t)dstl[e]*384;
            const float* ps = p1g + (size_t)srcl[e]*384;
            #pragma unroll
            for (int q = 0; q < 2; ++q){
                const int u = lane + q*64;
                float d0 = pd[u*3], d1 = pd[u*3+1], d2 = pd[u*3+2];
                float s0 = ps[u*3], s1 = ps[u*3+1], s2 = ps[u*3+2];
                ip1l[e][u] = (d0*s0 + d1*s1 + d2*s2) * (1.f/3.f);
            }
        }
    }
    // eal / sdl: one element per thread, coalesced in 32-groups
    {
        const int e = tid >> 5, k = tid & 31;
        eal[e][k] = ea[(size_t)eidl[e]*32 + k];
        sdl[e][k] = sdst[(size_t)dstl[e]*32 + k];
    }
    __syncthreads();

    // phase 2: dual GEMV (split accumulators to shorten dependency chains)
    {
        const int e = tid >> 5, h = tid & 31;
        float f0 = 0.f, f1 = 0.f;
        for (int k = 0; k < 32; k += 2){
            f0 += eal[e][k]   * Wf1[k*32 + h];
            f1 += eal[e][k+1] * Wf1[(k+1)*32 + h];
        }
        float sA = sdl[e][h], sB = 0.f;
        for (int u = 0; u < 128; u += 2){
            sA += ip1l[e][u]   * Ws1[(256+u)*32 + h];
            sB += ip1l[e][u+1] * Ws1[(257+u)*32 + h];
        }
        fbuf[(e0+e)*32 + h] = sspf(f0 + f1);
        sbuf[(e0+e)*32 + h] = sspf(sA + sB);
    }
}

// ---------------- fused edge GEMM + epilogue + segment reduction -----------
// Block = 64 CSR-ordered edges, 256 threads. Thread pair = channel c (0..127),
// half h. Each thread keeps 4 weight columns (128 VGPRs) for its 2 quadrants:
// h=0 -> (w1,w2), h=1 -> (w3,w4). Per edge: uniform LDS-broadcast fb/sb reads,
// 128 all-register FMA, one shfl_xor(1) to swap quadrant pairs. Outputs are
// accumulated in registers across each dst-segment (CSR-contiguous); interior
// segments direct-store, boundary segments atomicAdd to pre-zeroed out.
__global__ __launch_bounds__(256) void k_edge_one(
    const float* __restrict__ fbuf, const float* __restrict__ sbuf,
    const float* __restrict__ self_x, const float* __restrict__ esh,
    const int2* __restrict__ ebuf, const int* __restrict__ dstbuf,
    const float* __restrict__ Wf2, const float* __restrict__ Ws2,
    float* __restrict__ out)
{
    __shared__ float fbl[64][32];
    __shared__ float sbl[64][32];
    __shared__ float shl[64][4];
    __shared__ int   srcl[64], dl[64];

    const int tid = threadIdx.x;
    const int c   = tid >> 1;          // channel 0..127
    const int h   = tid & 1;           // half: 0 -> (w1,w2), 1 -> (w3,w4)
    const long e0 = (long)blockIdx.x * 64;
    const float IS3 = 0.57735026919f;

    // weight columns for quadrants qA=2h, qB=2h+1 (held in registers)
    float wfA[32], wfB[32], wsA[32], wsB[32];
    {
        const int qA = 2*h*128 + c, qB = (2*h+1)*128 + c;
        #pragma unroll
        for (int k = 0; k < 32; ++k){
            wfA[k] = Wf2[(size_t)k*512 + qA];
            wfB[k] = Wf2[(size_t)k*512 + qB];
            wsA[k] = Ws2[(size_t)k*512 + qA];
            wsB[k] = Ws2[(size_t)k*512 + qB];
        }
    }

    if (tid < 64){
        int2 pe = ebuf[e0 + tid];
        if (!(pe.x >= 0 && pe.x < EE)) pe.x = 0;
        if (!(pe.y >= 0 && pe.y < NN)) pe.y = 0;
        int d = dstbuf[e0 + tid];
        if (!(d >= 0 && d < NN)) d = 0;
        srcl[tid] = pe.y; dl[tid] = d;
        ((float4*)shl)[tid] = ((const float4*)esh)[pe.x];
    }
    { // fbuf/sbuf CSR-contiguous: fully coalesced copy, 512 float4 each
        const float4* fsrc = (const float4*)(fbuf + (size_t)e0*32);
        const float4* ssrc = (const float4*)(sbuf + (size_t)e0*32);
        ((float4*)fbl)[tid]       = fsrc[tid];
        ((float4*)fbl)[tid + 256] = fsrc[tid + 256];
        ((float4*)sbl)[tid]       = ssrc[tid];
        ((float4*)sbl)[tid + 256] = ssrc[tid + 256];
    }
    __syncthreads();

    // neighbor dsts for boundary detection (block-uniform)
    const int dprev = (blockIdx.x == 0)    ? -1 : dstbuf[e0 - 1];
    const int dnext = (e0 + 64 < EE)       ? dstbuf[e0 + 64] : -1;

    float a0 = 0.f, a1 = 0.f;
    int sstart = 0;

    // prefetch sx values for edge 0
    const float* sx0 = self_x + (size_t)srcl[0]*512;
    float px = sx0[c];
    float p0 = sx0[128 + 3*c];
    float p1v = sx0[128 + 3*c + 1];
    float p2 = sx0[128 + 3*c + 2];

    for (int e = 0; e < 64; ++e){
        const float x0c = px, v0 = p0, v1 = p1v, v2 = p2;
        if (e < 63){
            const float* sx = self_x + (size_t)srcl[e+1]*512;
            px  = sx[c];
            p0  = sx[128 + 3*c];
            p1v = sx[128 + 3*c + 1];
            p2  = sx[128 + 3*c + 2];
        }

        // dual quadrant dots (all-register FMA; fb/sb are LDS broadcasts)
        float FA = 0.f, FB = 0.f, SA = 0.f, SB = 0.f;
        #pragma unroll
        for (int k4 = 0; k4 < 8; ++k4){
            float4 fb4 = *(const float4*)&fbl[e][k4*4];
            float4 sb4 = *(const float4*)&sbl[e][k4*4];
            FA += fb4.x*wfA[k4*4+0]; FB += fb4.x*wfB[k4*4+0];
            SA += sb4.x*wsA[k4*4+0]; SB += sb4.x*wsB[k4*4+0];
            FA += fb4.y*wfA[k4*4+1]; FB += fb4.y*wfB[k4*4+1];
            SA += sb4.y*wsA[k4*4+1]; SB += sb4.y*wsB[k4*4+1];
            FA += fb4.z*wfA[k4*4+2]; FB += fb4.z*wfB[k4*4+2];
            SA += sb4.z*wsA[k4*4+2]; SB += sb4.z*wsB[k4*4+2];
            FA += fb4.w*wfA[k4*4+3]; FB += fb4.w*wfB[k4*4+3];
            SA += sb4.w*wsA[k4*4+3]; SB += sb4.w*wsB[k4*4+3];
        }
        const float wA = FA*SA, wB = FB*SB;
        const float oA = __shfl_xor(wA, 1);
        const float oB = __shfl_xor(wB, 1);
        // h=0: w1=wA w2=wB w3=oA w4=oB ; h=1: w1=oA w2=oB w3=wA w4=wB
        const float w1 = h ? oA : wA;
        const float w2 = h ? oB : wB;
        const float w3 = h ? wA : oA;
        const float w4 = h ? wB : oB;

        const float4 sh = *(const float4*)&shl[e][0];
        const int dste = dl[e];

        const float dot = v0*sh.y + v1*sh.z + v2*sh.w;
        // h=0: a0 = out0[c],    a1 = out1[c][0]
        // h=1: a0 = out1[c][1], a1 = out1[c][2]
        const float caw = h ? w2 : w1;
        const float cf  = h ? sh.z : sh.x;
        const float cbw = h ? w3 : w4*IS3;
        const float cg  = h ? v1*sh.x : dot;
        a0 += caw*x0c*cf + cbw*cg;
        const float shm = h ? sh.w : sh.y;
        const float vm  = h ? v2 : v0;
        a1 += w2*x0c*shm + w3*vm*sh.x;

        if (e == 63 || dl[e+1] != dste){   // block-uniform segment end
            const bool openL = (sstart == 0) && (dprev == dste);
            const bool openR = (e == 63) && (dnext == dste);
            float* orow = out + (size_t)dste*512;
            const int pos0 = h ? (128 + 3*c + 1) : c;
            const int pos1 = h ? (128 + 3*c + 2) : (128 + 3*c);
            if (openL || openR){
                atomicAdd(orow + pos0, a0);
                atomicAdd(orow + pos1, a1);
            } else {
                orow[pos0] = a0;
                orow[pos1] = a1;
            }
            a0 = 0.f; a1 = 0.f; sstart = e + 1;
        }
    }
}

// ---------------- K5: out linear + residual (in-place over d_out) ----------
__global__ __launch_bounds__(256) void k_post(
    const float* __restrict__ self_x, const float* __restrict__ x,
    const float* __restrict__ Wo0, const float* __restrict__ bo0,
    const float* __restrict__ Wo1,
    float* __restrict__ out)
{
    __shared__ float tl[512][8];
    const int tid = threadIdx.x;
    const int n0 = blockIdx.x * 8;

    for (int it = 0; it < 4; ++it){
        int idx = tid + 256*it;
        int node = idx >> 7, o4 = idx & 127;
        float4 a = ((const float4*)(out    + (size_t)(n0+node)*512))[o4];
        float4 b = ((const float4*)(self_x + (size_t)(n0+node)*512))[o4];
        tl[o4*4+0][node]=a.x+b.x; tl[o4*4+1][node]=a.y+b.y;
        tl[o4*4+2][node]=a.z+b.z; tl[o4*4+3][node]=a.w+b.w;
    }
    __syncthreads();

    const int j = tid;
    float acc1[8] = {0,0,0,0,0,0,0,0};
    float acc2[8] = {0,0,0,0,0,0,0,0};
    const int o2 = j + 128;
    const int v2 = o2/3, m2 = o2%3;
    if (j < 128){
        for (int u = 0; u < 128; ++u){
            float w1 = Wo0[u*128 + j];
            float w2 = Wo1[u*128 + v2];
            fma8(acc1, &tl[u][0], w1);
            fma8(acc2, &tl[128 + u*3 + m2][0], w2);
        }
        float b = bo0[j];
        #pragma unroll
        for (int n = 0; n < 8; ++n)
            out[(size_t)(n0+n)*512 + j] = acc1[n] + b + x[(size_t)(n0+n)*512 + j];
    } else {
        const int o1 = j - 128, v1 = o1/3, m1 = o1%3;
        for (int u = 0; u < 128; ++u){
            float w1 = Wo1[u*128 + v1];
            float w2 = Wo1[u*128 + v2];
            fma8(acc1, &tl[128 + u*3 + m1][0], w1);
            fma8(acc2, &tl[128 + u*3 + m2][0], w2);
        }
        #pragma unroll
        for (int n = 0; n < 8; ++n)
            out[(size_t)(n0+n)*512 + j] = acc1[n] + x[(size_t)(n0+n)*512 + j];
    }
    #pragma unroll
    for (int n = 0; n < 8; ++n)
        out[(size_t)(n0+n)*512 + j + 256] = acc2[n] + x[(size_t)(n0+n)*512 + j + 256];
}

// ---------------------------------------------------------------------------
extern "C" void kernel_launch(void* const* d_in, const int* in_sizes, int n_in,
                              void* d_out, int out_size, void* d_ws, size_t ws_size,
                              hipStream_t stream)
{
    const float* x    = (const float*)d_in[0];
    const float* esh  = (const float*)d_in[1];
    const float* ea   = (const float*)d_in[2];
    const int*   eidx = (const int*)  d_in[3];
    const float* Wp0  = (const float*)d_in[4];
    const float* bp0  = (const float*)d_in[5];
    const float* Wp1  = (const float*)d_in[6];
    const float* Wnd0 = (const float*)d_in[7];
    const float* bnd0 = (const float*)d_in[8];
    const float* Wnd1 = (const float*)d_in[9];
    const float* Wg1  = (const float*)d_in[10];
    const float* bg1  = (const float*)d_in[11];
    const float* Wg2  = (const float*)d_in[12];
    const float* bg2  = (const float*)d_in[13];
    const float* Wf1  = (const float*)d_in[14];
    const float* Wf2  = (const float*)d_in[15];
    const float* Ws1  = (const float*)d_in[16];
    const float* Ws2  = (const float*)d_in[17];
    const float* Wo0  = (const float*)d_in[18];
    const float* bo0  = (const float*)d_in[19];
    const float* Wo1  = (const float*)d_in[20];

    float* out  = (float*)d_out;
    float* ws   = (float*)d_ws;
    float* p1   = ws;                              // N*384 (dead after k_edge_pre)
    float* sdst = p1   + (size_t)NN*384;           // N*32
    float* sfx  = sdst + (size_t)NN*32;            // N*512
    float* fbuf = sfx  + (size_t)NN*512;           // E*32 (CSR-position order)
    float* sbuf = fbuf + (size_t)EE*32;            // E*32

    // CSR build arrays hosted in d_out (2.64 MB of 41 MB; out not needed yet)
    int*  dcnt  = (int*)d_out;                  // NN
    int*  dcur  = dcnt + NN;                    // NN
    int*  drow  = dcur + NN;                    // NN+1 (+3 pad for alignment)
    int2* debuf = (int2*)(drow + NN + 4);       // E int2 (byte 240016, 8-aligned)
    int*  ddst  = (int*)(debuf + EE);           // E int (contiguous after debuf)

    // CSR build first (needs only eidx)
    hipMemsetAsync(dcnt, 0, (size_t)NN*sizeof(int), stream);
    k_count <<<(EE+255)/256, 256, 0, stream>>>(eidx, dcnt);
    k_scan  <<<1, 256, 0, stream>>>(dcnt, drow, dcur);
    k_fill  <<<(EE+255)/256, 256, 0, stream>>>(eidx, dcur, debuf, ddst);

    k_pre     <<<NN/8, 256, 0, stream>>>(x, Wp0, bp0, Wp1, Ws1, p1, sdst);
    k_gate_nd <<<NN/8, 256, 0, stream>>>(x, Wg1, bg1, Wg2, bg2, Wnd0, bnd0, Wnd1, sfx);
    k_edge_pre<<<EE/8, 256, 0, stream>>>(p1, sdst, ea, debuf, ddst, Wf1, Ws1,
                                         fbuf, sbuf);

    // p1 now dead: move CSR (ebuf+dstbuf, contiguous 2.4 MB) into its region,
    // then zero out for the scatter.
    int2* ebuf2   = (int2*)ws;
    int*  dstbuf2 = (int*)ws + (size_t)2*EE;
    hipMemcpyAsync(ws, debuf, (size_t)3*EE*sizeof(int),
                   hipMemcpyDeviceToDevice, stream);
    hipMemsetAsync(out, 0, (size_t)NN*512*sizeof(float), stream);

    k_edge_one<<<EE/64, 256, 0, stream>>>(fbuf, sbuf, sfx, esh, ebuf2, dstbuf2,
                                          Wf2, Ws2, out);

    k_post    <<<NN/8, 256, 0, stream>>>(sfx, x, Wo0, bo0, Wo1, out);
}

// Round 5
// 947.848 us; speedup vs baseline: 1.1800x; 1.1800x over previous
//
#include <hip/hip_runtime.h>
#include <hip/hip_fp16.h>
#include <math.h>

#define NN 20000
#define EE 200000
// MUL=128, D=512, EDGE_ATTR=32, HID=32

__device__ __forceinline__ float sspf(float x){
    float sp = (x > 20.f) ? x : log1pf(expf(x));
    return sp - 0.69314718056f;
}

__device__ __forceinline__ void fma8(float* acc, const float* base, float w){
    const float4 a = ((const float4*)base)[0];
    const float4 b = ((const float4*)base)[1];
    acc[0]+=a.x*w; acc[1]+=a.y*w; acc[2]+=a.z*w; acc[3]+=a.w*w;
    acc[4]+=b.x*w; acc[5]+=b.y*w; acc[6]+=b.z*w; acc[7]+=b.w*w;
}

// ---------------- K1: pre irrep_linear -> p1, sdst (p0 consumed in-LDS) ----
__global__ __launch_bounds__(256) void k_pre(
    const float* __restrict__ x, const float* __restrict__ Wp0,
    const float* __restrict__ bp0, const float* __restrict__ Wp1,
    const float* __restrict__ Ws1,
    float* __restrict__ p1, float* __restrict__ sdst)
{
    __shared__ float xl[512][8];    // transposed [feature][node]
    __shared__ float p0l[8][128];
    const int tid = threadIdx.x;
    const int n0 = blockIdx.x * 8;

    for (int it = 0; it < 4; ++it){
        int idx = tid + 256*it;           // 0..1023 float4 slots
        int node = idx >> 7, o4 = idx & 127;
        float4 v = ((const float4*)(x + (size_t)(n0+node)*512))[o4];
        xl[o4*4+0][node]=v.x; xl[o4*4+1][node]=v.y;
        xl[o4*4+2][node]=v.z; xl[o4*4+3][node]=v.w;
    }
    __syncthreads();

    const int j = tid;
    float acc1[8] = {0,0,0,0,0,0,0,0};
    float acc2[8] = {0,0,0,0,0,0,0,0};
    const int o2 = j + 128;               // p1-index in [128,384)
    const int v2 = o2/3, m2 = o2%3;

    if (j < 128){
        for (int u = 0; u < 128; ++u){
            float w1 = Wp0[u*128 + j];
            float w2 = Wp1[u*128 + v2];
            fma8(acc1, &xl[u][0], w1);
            fma8(acc2, &xl[128 + u*3 + m2][0], w2);
        }
        float b = bp0[j];
        #pragma unroll
        for (int n = 0; n < 8; ++n) p0l[n][j] = acc1[n] + b;
    } else {
        const int o1 = j - 128, v1 = o1/3, m1 = o1%3;
        for (int u = 0; u < 128; ++u){
            float w1 = Wp1[u*128 + v1];
            float w2 = Wp1[u*128 + v2];
            fma8(acc1, &xl[128 + u*3 + m1][0], w1);
            fma8(acc2, &xl[128 + u*3 + m2][0], w2);
        }
        #pragma unroll
        for (int n = 0; n < 8; ++n) p1[(size_t)(n0+n)*384 + (j-128)] = acc1[n];
    }
    #pragma unroll
    for (int n = 0; n < 8; ++n) p1[(size_t)(n0+n)*384 + o2] = acc2[n];
    __syncthreads();

    // sdst = p0 @ (Ws1[0:128] + Ws1[128:256])  (the dst-only part of s0@W_s1)
    {
        int n = tid >> 5, h = tid & 31;
        float s = 0.f;
        for (int u = 0; u < 128; ++u){
            float wc = Ws1[u*32 + h] + Ws1[(128+u)*32 + h];
            s += p0l[n][u] * wc;
        }
        sdst[(size_t)(n0+n)*32 + h] = s;
    }
}

// ---------------- K2: gate + node irrep_linear -> self_x -------------------
__global__ __launch_bounds__(256) void k_gate_nd(
    const float* __restrict__ x,
    const float* __restrict__ Wg1, const float* __restrict__ bg1,
    const float* __restrict__ Wg2, const float* __restrict__ bg2,
    const float* __restrict__ Wnd0, const float* __restrict__ bnd0,
    const float* __restrict__ Wnd1,
    float* __restrict__ self_x)
{
    __shared__ float xl[512][8];
    __shared__ float tl[256][8];   // t, then reused for g
    __shared__ float hl[256][8];
    const int tid = threadIdx.x;
    const int n0 = blockIdx.x * 8;

    for (int it = 0; it < 4; ++it){
        int idx = tid + 256*it;
        int node = idx >> 7, o4 = idx & 127;
        float4 v = ((const float4*)(x + (size_t)(n0+node)*512))[o4];
        xl[o4*4+0][node]=v.x; xl[o4*4+1][node]=v.y;
        xl[o4*4+2][node]=v.z; xl[o4*4+3][node]=v.w;
    }
    __syncthreads();

    { // t = [x0, n1]
        int jj = tid;
        if (jj < 128){
            #pragma unroll
            for (int n = 0; n < 8; ++n) tl[jj][n] = xl[jj][n];
        } else {
            int u = jj - 128;
            #pragma unroll
            for (int n = 0; n < 8; ++n){
                float a = xl[128+u*3][n], b = xl[128+u*3+1][n], c = xl[128+u*3+2][n];
                tl[jj][n] = sqrtf((a*a + b*b + c*c) * (1.f/3.f));
            }
        }
    }
    __syncthreads();

    { // h = silu(t @ Wg1 + bg1)
        float acc[8] = {0,0,0,0,0,0,0,0};
        for (int k = 0; k < 256; ++k){
            float w = Wg1[k*256 + tid];
            fma8(acc, &tl[k][0], w);
        }
        float b = bg1[tid];
        #pragma unroll
        for (int n = 0; n < 8; ++n){
            float v = acc[n] + b;
            hl[tid][n] = v / (1.f + expf(-v));
        }
    }
    __syncthreads();

    { // g = h @ Wg2 + bg2  (stored into tl; tl is dead after the barrier)
        float acc[8] = {0,0,0,0,0,0,0,0};
        for (int k = 0; k < 256; ++k){
            float w = Wg2[k*256 + tid];
            fma8(acc, &hl[k][0], w);
        }
        float b = bg2[tid];
        #pragma unroll
        for (int n = 0; n < 8; ++n) tl[tid][n] = acc[n] + b;
    }
    __syncthreads();

    { // xg in-place into xl
        int jj = tid;
        if (jj < 128){
            #pragma unroll
            for (int n = 0; n < 8; ++n) xl[jj][n] = tl[jj][n];
        } else {
            int u = jj - 128;
            #pragma unroll
            for (int n = 0; n < 8; ++n){
                float g1 = tl[128+u][n];
                xl[128+u*3  ][n] *= g1;
                xl[128+u*3+1][n] *= g1;
                xl[128+u*3+2][n] *= g1;
            }
        }
    }
    __syncthreads();

    // nd irrep_linear
    const int j = tid;
    float acc1[8] = {0,0,0,0,0,0,0,0};
    float acc2[8] = {0,0,0,0,0,0,0,0};
    const int o2 = j + 128;
    const int v2 = o2/3, m2 = o2%3;
    if (j < 128){
        for (int u = 0; u < 128; ++u){
            float w1 = Wnd0[u*128 + j];
            float w2 = Wnd1[u*128 + v2];
            fma8(acc1, &xl[u][0], w1);
            fma8(acc2, &xl[128 + u*3 + m2][0], w2);
        }
        float b = bnd0[j];
        #pragma unroll
        for (int n = 0; n < 8; ++n) self_x[(size_t)(n0+n)*512 + j] = acc1[n] + b;
    } else {
        const int o1 = j - 128, v1 = o1/3, m1 = o1%3;
        for (int u = 0; u < 128; ++u){
            float w1 = Wnd1[u*128 + v1];
            float w2 = Wnd1[u*128 + v2];
            fma8(acc1, &xl[128 + u*3 + m1][0], w1);
            fma8(acc2, &xl[128 + u*3 + m2][0], w2);
        }
        #pragma unroll
        for (int n = 0; n < 8; ++n) self_x[(size_t)(n0+n)*512 + j] = acc1[n];
    }
    #pragma unroll
    for (int n = 0; n < 8; ++n) self_x[(size_t)(n0+n)*512 + j + 256] = acc2[n];
}

// ---------------- CSR build: count, scan, fill (arrays hosted in d_out) ----
__global__ __launch_bounds__(256) void k_count(
    const int* __restrict__ eidx, int* __restrict__ cnt)
{
    int e = blockIdx.x * 256 + threadIdx.x;
    if (e < EE){
        int d = eidx[e];
        if (d >= 0 && d < NN) atomicAdd(&cnt[d], 1);
    }
}

__global__ __launch_bounds__(256) void k_scan(
    const int* __restrict__ cnt, int* __restrict__ rowptr, int* __restrict__ cur)
{
    __shared__ int part[256];
    const int t = threadIdx.x;
    const int CHUNK = 79;             // 256*79 = 20224 >= 20000
    const int base = t * CHUNK;
    int s = 0;
    for (int i = 0; i < CHUNK; ++i){
        int idx = base + i;
        if (idx < NN) s += cnt[idx];
    }
    part[t] = s;
    __syncthreads();
    for (int off = 1; off < 256; off <<= 1){
        int v = (t >= off) ? part[t-off] : 0;
        __syncthreads();
        part[t] += v;
        __syncthreads();
    }
    int run = (t == 0) ? 0 : part[t-1];
    for (int i = 0; i < CHUNK; ++i){
        int idx = base + i;
        if (idx < NN){
            rowptr[idx] = run;
            cur[idx]    = run;
            run += cnt[idx];
        }
    }
    if (t == 255) rowptr[NN] = run;
}

__global__ __launch_bounds__(256) void k_fill(
    const int* __restrict__ eidx, int* __restrict__ cur, int2* __restrict__ ebuf,
    int* __restrict__ dstbuf)
{
    int e = blockIdx.x * 256 + threadIdx.x;
    if (e < EE){
        int dst = eidx[e];
        int src = eidx[EE + e];
        if (dst >= 0 && dst < NN){
            int pos = atomicAdd(&cur[dst], 1);
            if (pos >= 0 && pos < EE){
                ebuf[pos] = make_int2(e, src);
                dstbuf[pos] = dst;
            }
        }
    }
}

// ---------------- K3: edge features in CSR order -> fbuf, sbuf -------------
// Wave-per-edge: lane l computes ip1 for channels 2l,2l+1 from 24B contiguous
// slices of p1[dst]/p1[src] (wave reads each 1536B row fully coalesced, rows
// never staged), writes 2 floats to wave-private LDS. GEMVs split across the
// two half-waves (64/16 iters) + one shfl_xor(32) combine. Tiny register
// footprint by construction; LDS 2KB/block.
__global__ __launch_bounds__(256, 4) void k_edge_pre(
    const float* __restrict__ p1g, const float* __restrict__ sdst,
    const float* __restrict__ ea,
    const int2* __restrict__ ebuf, const int* __restrict__ dstbuf,
    const float* __restrict__ Wf1, const float* __restrict__ Ws1,
    float* __restrict__ fbuf, float* __restrict__ sbuf)
{
    __shared__ float ipw[4][128];
    const int tid  = threadIdx.x;
    const int wv   = tid >> 6, lane = tid & 63;
    const long e   = (long)blockIdx.x * 4 + wv;

    int2 pe = ebuf[e];
    if (!(pe.x >= 0 && pe.x < EE)) pe.x = 0;   // defensive (poison-safe)
    if (!(pe.y >= 0 && pe.y < NN)) pe.y = 0;
    int dst = dstbuf[e];
    if (!(dst >= 0 && dst < NN)) dst = 0;

    // channels u = 2*lane, 2*lane+1  ->  p1 row bytes [24*lane, 24*lane+24)
    const float* pd = p1g + (size_t)dst*384 + lane*6;
    const float* ps = p1g + (size_t)pe.y*384 + lane*6;
    const float2 d01 = *(const float2*)(pd);
    const float2 d23 = *(const float2*)(pd+2);
    const float2 d45 = *(const float2*)(pd+4);
    const float2 s01 = *(const float2*)(ps);
    const float2 s23 = *(const float2*)(ps+2);
    const float2 s45 = *(const float2*)(ps+4);
    const float ipa = (d01.x*s01.x + d01.y*s01.y + d23.x*s23.x) * (1.f/3.f);
    const float ipb = (d23.y*s23.y + d45.x*s45.x + d45.y*s45.y) * (1.f/3.f);
    *(float2*)&ipw[wv][lane*2] = make_float2(ipa, ipb);

    const int h = lane & 31;
    const float sdv = sdst[(size_t)dst*32 + h];   // broadcast per half-wave

    __syncthreads();

    // s-GEMV: half-wave u-split (lane>=32 -> u in [64,128))
    const int uh = (lane >> 5) * 64;
    float sA = 0.f, sB = 0.f;
    #pragma unroll 8
    for (int uu = 0; uu < 64; uu += 2){
        sA += ipw[wv][uh+uu]   * Ws1[(256+uh+uu)*32 + h];
        sB += ipw[wv][uh+uu+1] * Ws1[(257+uh+uu)*32 + h];
    }
    float s = sA + sB;
    s += __shfl_xor(s, 32);

    // f-GEMV: half-wave k-split (16 iters each)
    const int kh = (lane >> 5) * 16;
    const float* ear = ea + (size_t)pe.x*32 + kh;
    float f = 0.f;
    #pragma unroll 8
    for (int kk = 0; kk < 16; ++kk)
        f += ear[kk] * Wf1[(kh+kk)*32 + h];
    f += __shfl_xor(f, 32);

    if (lane < 32){
        sbuf[e*32 + h] = sspf(s + sdv);
        fbuf[e*32 + h] = sspf(f);
    }
}

// ---------------- fused edge GEMM + epilogue + segment reduction -----------
// Block = 64 CSR-ordered edges, 256 threads. Thread pair = channel c (0..127),
// half h. Each thread keeps 4 weight columns (128 VGPRs) for its 2 quadrants:
// h=0 -> (w1,w2), h=1 -> (w3,w4). Per edge: uniform LDS-broadcast fb/sb reads,
// 128 all-register FMA, one shfl_xor(1) to swap quadrant pairs. Outputs are
// accumulated in registers across each dst-segment (CSR-contiguous); interior
// segments direct-store, boundary segments atomicAdd to pre-zeroed out.
__global__ __launch_bounds__(256) void k_edge_one(
    const float* __restrict__ fbuf, const float* __restrict__ sbuf,
    const float* __restrict__ self_x, const float* __restrict__ esh,
    const int2* __restrict__ ebuf, const int* __restrict__ dstbuf,
    const float* __restrict__ Wf2, const float* __restrict__ Ws2,
    float* __restrict__ out)
{
    __shared__ float fbl[64][32];
    __shared__ float sbl[64][32];
    __shared__ float shl[64][4];
    __shared__ int   srcl[64], dl[64];

    const int tid = threadIdx.x;
    const int c   = tid >> 1;          // channel 0..127
    const int h   = tid & 1;           // half: 0 -> (w1,w2), 1 -> (w3,w4)
    const long e0 = (long)blockIdx.x * 64;
    const float IS3 = 0.57735026919f;

    // weight columns for quadrants qA=2h, qB=2h+1 (held in registers)
    float wfA[32], wfB[32], wsA[32], wsB[32];
    {
        const int qA = 2*h*128 + c, qB = (2*h+1)*128 + c;
        #pragma unroll
        for (int k = 0; k < 32; ++k){
            wfA[k] = Wf2[(size_t)k*512 + qA];
            wfB[k] = Wf2[(size_t)k*512 + qB];
            wsA[k] = Ws2[(size_t)k*512 + qA];
            wsB[k] = Ws2[(size_t)k*512 + qB];
        }
    }

    if (tid < 64){
        int2 pe = ebuf[e0 + tid];
        if (!(pe.x >= 0 && pe.x < EE)) pe.x = 0;
        if (!(pe.y >= 0 && pe.y < NN)) pe.y = 0;
        int d = dstbuf[e0 + tid];
        if (!(d >= 0 && d < NN)) d = 0;
        srcl[tid] = pe.y; dl[tid] = d;
        ((float4*)shl)[tid] = ((const float4*)esh)[pe.x];
    }
    { // fbuf/sbuf CSR-contiguous: fully coalesced copy, 512 float4 each
        const float4* fsrc = (const float4*)(fbuf + (size_t)e0*32);
        const float4* ssrc = (const float4*)(sbuf + (size_t)e0*32);
        ((float4*)fbl)[tid]       = fsrc[tid];
        ((float4*)fbl)[tid + 256] = fsrc[tid + 256];
        ((float4*)sbl)[tid]       = ssrc[tid];
        ((float4*)sbl)[tid + 256] = ssrc[tid + 256];
    }
    __syncthreads();

    // neighbor dsts for boundary detection (block-uniform)
    const int dprev = (blockIdx.x == 0)    ? -1 : dstbuf[e0 - 1];
    const int dnext = (e0 + 64 < EE)       ? dstbuf[e0 + 64] : -1;

    float a0 = 0.f, a1 = 0.f;
    int sstart = 0;

    // prefetch sx values for edge 0
    const float* sx0 = self_x + (size_t)srcl[0]*512;
    float px = sx0[c];
    float p0 = sx0[128 + 3*c];
    float p1v = sx0[128 + 3*c + 1];
    float p2 = sx0[128 + 3*c + 2];

    for (int e = 0; e < 64; ++e){
        const float x0c = px, v0 = p0, v1 = p1v, v2 = p2;
        if (e < 63){
            const float* sx = self_x + (size_t)srcl[e+1]*512;
            px  = sx[c];
            p0  = sx[128 + 3*c];
            p1v = sx[128 + 3*c + 1];
            p2  = sx[128 + 3*c + 2];
        }

        // dual quadrant dots (all-register FMA; fb/sb are LDS broadcasts)
        float FA = 0.f, FB = 0.f, SA = 0.f, SB = 0.f;
        #pragma unroll
        for (int k4 = 0; k4 < 8; ++k4){
            float4 fb4 = *(const float4*)&fbl[e][k4*4];
            float4 sb4 = *(const float4*)&sbl[e][k4*4];
            FA += fb4.x*wfA[k4*4+0]; FB += fb4.x*wfB[k4*4+0];
            SA += sb4.x*wsA[k4*4+0]; SB += sb4.x*wsB[k4*4+0];
            FA += fb4.y*wfA[k4*4+1]; FB += fb4.y*wfB[k4*4+1];
            SA += sb4.y*wsA[k4*4+1]; SB += sb4.y*wsB[k4*4+1];
            FA += fb4.z*wfA[k4*4+2]; FB += fb4.z*wfB[k4*4+2];
            SA += sb4.z*wsA[k4*4+2]; SB += sb4.z*wsB[k4*4+2];
            FA += fb4.w*wfA[k4*4+3]; FB += fb4.w*wfB[k4*4+3];
            SA += sb4.w*wsA[k4*4+3]; SB += sb4.w*wsB[k4*4+3];
        }
        const float wA = FA*SA, wB = FB*SB;
        const float oA = __shfl_xor(wA, 1);
        const float oB = __shfl_xor(wB, 1);
        // h=0: w1=wA w2=wB w3=oA w4=oB ; h=1: w1=oA w2=oB w3=wA w4=wB
        const float w1 = h ? oA : wA;
        const float w2 = h ? oB : wB;
        const float w3 = h ? wA : oA;
        const float w4 = h ? wB : oB;

        const float4 sh = *(const float4*)&shl[e][0];
        const int dste = dl[e];

        const float dot = v0*sh.y + v1*sh.z + v2*sh.w;
        // h=0: a0 = out0[c],    a1 = out1[c][0]
        // h=1: a0 = out1[c][1], a1 = out1[c][2]
        const float caw = h ? w2 : w1;
        const float cf  = h ? sh.z : sh.x;
        const float cbw = h ? w3 : w4*IS3;
        const float cg  = h ? v1*sh.x : dot;
        a0 += caw*x0c*cf + cbw*cg;
        const float shm = h ? sh.w : sh.y;
        const float vm  = h ? v2 : v0;
        a1 += w2*x0c*shm + w3*vm*sh.x;

        if (e == 63 || dl[e+1] != dste){   // block-uniform segment end
            const bool openL = (sstart == 0) && (dprev == dste);
            const bool openR = (e == 63) && (dnext == dste);
            float* orow = out + (size_t)dste*512;
            const int pos0 = h ? (128 + 3*c + 1) : c;
            const int pos1 = h ? (128 + 3*c + 2) : (128 + 3*c);
            if (openL || openR){
                atomicAdd(orow + pos0, a0);
                atomicAdd(orow + pos1, a1);
            } else {
                orow[pos0] = a0;
                orow[pos1] = a1;
            }
            a0 = 0.f; a1 = 0.f; sstart = e + 1;
        }
    }
}

// ---------------- K5: out linear + residual (in-place over d_out) ----------
__global__ __launch_bounds__(256) void k_post(
    const float* __restrict__ self_x, const float* __restrict__ x,
    const float* __restrict__ Wo0, const float* __restrict__ bo0,
    const float* __restrict__ Wo1,
    float* __restrict__ out)
{
    __shared__ float tl[512][8];
    const int tid = threadIdx.x;
    const int n0 = blockIdx.x * 8;

    for (int it = 0; it < 4; ++it){
        int idx = tid + 256*it;
        int node = idx >> 7, o4 = idx & 127;
        float4 a = ((const float4*)(out    + (size_t)(n0+node)*512))[o4];
        float4 b = ((const float4*)(self_x + (size_t)(n0+node)*512))[o4];
        tl[o4*4+0][node]=a.x+b.x; tl[o4*4+1][node]=a.y+b.y;
        tl[o4*4+2][node]=a.z+b.z; tl[o4*4+3][node]=a.w+b.w;
    }
    __syncthreads();

    const int j = tid;
    float acc1[8] = {0,0,0,0,0,0,0,0};
    float acc2[8] = {0,0,0,0,0,0,0,0};
    const int o2 = j + 128;
    const int v2 = o2/3, m2 = o2%3;
    if (j < 128){
        for (int u = 0; u < 128; ++u){
            float w1 = Wo0[u*128 + j];
            float w2 = Wo1[u*128 + v2];
            fma8(acc1, &tl[u][0], w1);
            fma8(acc2, &tl[128 + u*3 + m2][0], w2);
        }
        float b = bo0[j];
        #pragma unroll
        for (int n = 0; n < 8; ++n)
            out[(size_t)(n0+n)*512 + j] = acc1[n] + b + x[(size_t)(n0+n)*512 + j];
    } else {
        const int o1 = j - 128, v1 = o1/3, m1 = o1%3;
        for (int u = 0; u < 128; ++u){
            float w1 = Wo1[u*128 + v1];
            float w2 = Wo1[u*128 + v2];
            fma8(acc1, &tl[128 + u*3 + m1][0], w1);
            fma8(acc2, &tl[128 + u*3 + m2][0], w2);
        }
        #pragma unroll
        for (int n = 0; n < 8; ++n)
            out[(size_t)(n0+n)*512 + j] = acc1[n] + x[(size_t)(n0+n)*512 + j];
    }
    #pragma unroll
    for (int n = 0; n < 8; ++n)
        out[(size_t)(n0+n)*512 + j + 256] = acc2[n] + x[(size_t)(n0+n)*512 + j + 256];
}

// ---------------------------------------------------------------------------
extern "C" void kernel_launch(void* const* d_in, const int* in_sizes, int n_in,
                              void* d_out, int out_size, void* d_ws, size_t ws_size,
                              hipStream_t stream)
{
    const float* x    = (const float*)d_in[0];
    const float* esh  = (const float*)d_in[1];
    const float* ea   = (const float*)d_in[2];
    const int*   eidx = (const int*)  d_in[3];
    const float* Wp0  = (const float*)d_in[4];
    const float* bp0  = (const float*)d_in[5];
    const float* Wp1  = (const float*)d_in[6];
    const float* Wnd0 = (const float*)d_in[7];
    const float* bnd0 = (const float*)d_in[8];
    const float* Wnd1 = (const float*)d_in[9];
    const float* Wg1  = (const float*)d_in[10];
    const float* bg1  = (const float*)d_in[11];
    const float* Wg2  = (const float*)d_in[12];
    const float* bg2  = (const float*)d_in[13];
    const float* Wf1  = (const float*)d_in[14];
    const float* Wf2  = (const float*)d_in[15];
    const float* Ws1  = (const float*)d_in[16];
    const float* Ws2  = (const float*)d_in[17];
    const float* Wo0  = (const float*)d_in[18];
    const float* bo0  = (const float*)d_in[19];
    const float* Wo1  = (const float*)d_in[20];

    float* out  = (float*)d_out;
    float* ws   = (float*)d_ws;
    float* p1   = ws;                              // N*384 (dead after k_edge_pre)
    float* sdst = p1   + (size_t)NN*384;           // N*32
    float* sfx  = sdst + (size_t)NN*32;            // N*512
    float* fbuf = sfx  + (size_t)NN*512;           // E*32 (CSR-position order)
    float* sbuf = fbuf + (size_t)EE*32;            // E*32

    // CSR build arrays hosted in d_out (2.64 MB of 41 MB; out not needed yet)
    int*  dcnt  = (int*)d_out;                  // NN
    int*  dcur  = dcnt + NN;                    // NN
    int*  drow  = dcur + NN;                    // NN+1 (+3 pad for alignment)
    int2* debuf = (int2*)(drow + NN + 4);       // E int2 (byte 240016, 8-aligned)
    int*  ddst  = (int*)(debuf + EE);           // E int (contiguous after debuf)

    // CSR build first (needs only eidx)
    hipMemsetAsync(dcnt, 0, (size_t)NN*sizeof(int), stream);
    k_count <<<(EE+255)/256, 256, 0, stream>>>(eidx, dcnt);
    k_scan  <<<1, 256, 0, stream>>>(dcnt, drow, dcur);
    k_fill  <<<(EE+255)/256, 256, 0, stream>>>(eidx, dcur, debuf, ddst);

    k_pre     <<<NN/8, 256, 0, stream>>>(x, Wp0, bp0, Wp1, Ws1, p1, sdst);
    k_gate_nd <<<NN/8, 256, 0, stream>>>(x, Wg1, bg1, Wg2, bg2, Wnd0, bnd0, Wnd1, sfx);
    k_edge_pre<<<EE/4, 256, 0, stream>>>(p1, sdst, ea, debuf, ddst, Wf1, Ws1,
                                         fbuf, sbuf);

    // p1 now dead: move CSR (ebuf+dstbuf, contiguous 2.4 MB) into its region,
    // then zero out for the scatter.
    int2* ebuf2   = (int2*)ws;
    int*  dstbuf2 = (int*)ws + (size_t)2*EE;
    hipMemcpyAsync(ws, debuf, (size_t)3*EE*sizeof(int),
                   hipMemcpyDeviceToDevice, stream);
    hipMemsetAsync(out, 0, (size_t)NN*512*sizeof(float), stream);

    k_edge_one<<<EE/64, 256, 0, stream>>>(fbuf, sbuf, sfx, esh, ebuf2, dstbuf2,
                                          Wf2, Ws2, out);

    k_post    <<<NN/8, 256, 0, stream>>>(sfx, x, Wo0, bo0, Wo1, out);
}